// Round 11
// baseline (24.467 us; speedup 1.0000x reference)
//
#include <hip/hip_runtime.h>
#include <hip/hip_bf16.h>
#include <hip/hip_fp16.h>
#include <math.h>

// Inverse Radon backprojection: r8 structure + fp16 quad taps + 1-deep
// software pipeline.  sinogram (B,180,512) fp32; angles deg; out (B,1,512,512).
//
// Structure (r8, best=20.4us): block = 16x16 tile of antipodal pixel PAIRS,
// 1024 threads = 4/pair (quarter q sums angles [45q,45q+45)), LDS tree-
// combine. 512 blocks -> 2 blocks/CU x 16 waves = 32 waves/CU.
//
// Round history: r9 readlane consts REGRESSED (SGPR-write hazards);
// r10 quad+split-consts REGRESSED (const b128 split into 2 reads + 4 cvts
// on the load->use chain). This round keeps r8's single b128 const and adds
// ONLY:
//  - fp16 quad window, PRE-SHUFFLED {g0,v},{g1,u}: slot gi of angle n holds
//    lo2={s[gi],s[511-gi]}, hi2={s[gi+1],s[510-gi]} -> ONE ds_read_b64 gives
//    both mirrored pixels' taps; valA = lo.x + w1*(hi.x-lo.x),
//    valB = lo.y + w1*(hi.y-lo.y)  (exact mirror identity, r10-validated).
//    B-side floor/cvt/addr chain eliminated.
//  - manual 1-deep pipeline: while consuming iteration k's taps, prefetch
//    const+coords for k+1 (taps are not prefetchable: address is data-
//    dependent). Peeled last iteration.
//
// Validated identities (r2..r10): zero-filled windows == reference
// mask*gather; yw = sat(iy+1)*sat(512-iy); mirror ix'=511-ix, yw'==yw.

#define IRD_W 512
#define IRD_N 180
#define WIN   32
#define QN    45
#define IRD_STEP (2.0f / 511.0f)

__global__ __launch_bounds__(1024, 8) void iradon_quadp_kernel(
    const float* __restrict__ sino,    // B*N*W
    const float* __restrict__ angles,  // N
    float* __restrict__ out)           // B*H*W
{
    __shared__ float4 s_c[IRD_N];            // {ch, sh, 255.5-baseA, 255.5}
    __shared__ int    s_base[IRD_N];         // baseA
    __shared__ uint2  s_quad[IRD_N * WIN];   // {lo2, hi2} fp16 quads, 8B/slot
    __shared__ float  s_redA[3][256];
    __shared__ float  s_redB[3][256];

    const int tid = threadIdx.x;
    const int x0 = (blockIdx.x & 31) << 4;
    const int y0 = (blockIdx.x >> 5) << 4;   // y0 in [0,256)
    const int b  = blockIdx.y;

    const float h = 255.5f;
    const float xs0 = -1.0f + (float)x0 * IRD_STEP;
    const float ys0 = -1.0f + (float)y0 * IRD_STEP;
    const float xs1 = xs0 + 15.0f * IRD_STEP;
    const float ys1 = ys0 + 15.0f * IRD_STEP;

    if (tid < IRD_N) {
        float th = angles[tid] * 0.017453292519943295f;
        float sv, cv;
        sincosf(th, &sv, &cv);
        const float ch = cv * h, sh = sv * h;
        const float cx0 = ch * xs0, cx1 = ch * xs1;
        const float sy0 = sh * ys0, sy1 = sh * ys1;
        const float minA = fminf(cx0, cx1) + fminf(sy0, sy1) + h;
        const int baseA = (int)floorf(minA) - 1;
        s_c[tid] = make_float4(ch, sh, h - (float)baseA, h);
        s_base[tid] = baseA;
    }
    __syncthreads();

    // Stage fp16 quads: slot (n,i), gi = baseA+i:
    //   lo2 = {s[gi], s[511-gi]},  hi2 = {s[gi+1], s[510-gi]}
    // each element zero-filled by its own bounds (== reference masks).
    const float* __restrict__ sb = sino + (size_t)b * (IRD_N * IRD_W);
    for (int idx = tid; idx < IRD_N * WIN; idx += 1024) {
        const int n  = idx >> 5;
        const int i  = idx & (WIN - 1);
        const int gi = s_base[n] + i;
        const float* __restrict__ row = sb + n * IRD_W;
        const float g0 = ((unsigned)gi         < IRD_W) ? row[gi]       : 0.0f;
        const float g1 = ((unsigned)(gi + 1)   < IRD_W) ? row[gi + 1]   : 0.0f;
        const float u  = ((unsigned)(510 - gi) < IRD_W) ? row[510 - gi] : 0.0f;
        const float v  = ((unsigned)(511 - gi) < IRD_W) ? row[511 - gi] : 0.0f;
        const __half2 lo2 = __float22half2_rn(make_float2(g0, v));
        const __half2 hi2 = __float22half2_rn(make_float2(g1, u));
        s_quad[idx] = make_uint2(__builtin_bit_cast(unsigned, lo2),
                                 __builtin_bit_cast(unsigned, hi2));
    }
    __syncthreads();

    const int p = tid & 255;
    const int q = tid >> 8;
    const int n0 = q * QN;
    const int x = x0 + (p & 15);
    const int y = y0 + (p >> 4);
    const float xs = -1.0f + (float)x * IRD_STEP;
    const float ys = -1.0f + (float)y * IRD_STEP;
    const float xsn = -xs;

    const uint2* __restrict__ qbase = &s_quad[n0 << 5];

    float accA = 0.0f, accB = 0.0f;

    // prologue: coords for k=0
    float4 c = s_c[n0];
    float ixr = fmaf(c.x, xs, fmaf(c.y, ys, c.z));   // ix - baseA, in [1,25)
    float iy  = fmaf(c.x, ys, fmaf(c.y, xsn, h));    // absolute

    #pragma unroll 4
    for (int k = 0; k < QN - 1; ++k) {
        const float fg = floorf(ixr);
        const float w1 = ixr - fg;
        const uint2 q2 = qbase[(k << 5) + (int)fg];  // taps for BOTH pixels
        const float yw = __saturatef(iy + 1.0f) * __saturatef(512.0f - iy);

        // prefetch k+1 const + coords (hides q2 latency)
        const float4 cn = s_c[n0 + k + 1];
        const float ixr_n = fmaf(cn.x, xs, fmaf(cn.y, ys, cn.z));
        const float iy_n  = fmaf(cn.x, ys, fmaf(cn.y, xsn, h));

        const float2 lo = __half22float2(__builtin_bit_cast(__half2, q2.x));
        const float2 hi = __half22float2(__builtin_bit_cast(__half2, q2.y));
        accA = fmaf(fmaf(w1, hi.x - lo.x, lo.x), yw, accA);
        accB = fmaf(fmaf(w1, hi.y - lo.y, lo.y), yw, accB);

        ixr = ixr_n;
        iy  = iy_n;
    }
    {   // peeled k = QN-1 (no prefetch)
        const float fg = floorf(ixr);
        const float w1 = ixr - fg;
        const uint2 q2 = qbase[((QN - 1) << 5) + (int)fg];
        const float yw = __saturatef(iy + 1.0f) * __saturatef(512.0f - iy);
        const float2 lo = __half22float2(__builtin_bit_cast(__half2, q2.x));
        const float2 hi = __half22float2(__builtin_bit_cast(__half2, q2.y));
        accA = fmaf(fmaf(w1, hi.x - lo.x, lo.x), yw, accA);
        accB = fmaf(fmaf(w1, hi.y - lo.y, lo.y), yw, accB);
    }

    if (q != 0) {
        s_redA[q - 1][p] = accA;
        s_redB[q - 1][p] = accB;
    }
    __syncthreads();

    if (q == 0) {
        accA = ((accA + s_redA[0][p]) + s_redA[1][p]) + s_redA[2][p];
        accB = ((accB + s_redB[0][p]) + s_redB[1][p]) + s_redB[2][p];
        const int ob = b << 18;
        out[ob + (y << 9) + x]                 = accA * (1.0f / 180.0f);
        out[ob + ((511 - y) << 9) + (511 - x)] = accB * (1.0f / 180.0f);
    }
}

extern "C" void kernel_launch(void* const* d_in, const int* in_sizes, int n_in,
                              void* d_out, int out_size, void* d_ws, size_t ws_size,
                              hipStream_t stream) {
    const float* sino = (const float*)d_in[0];
    const float* angles = (const float*)d_in[1];
    float* out = (float*)d_out;

    const int B = out_size >> 18;            // H*W == 2^18
    dim3 grid(512, B > 0 ? B : 1);
    iradon_quadp_kernel<<<grid, 1024, 0, stream>>>(sino, angles, out);
}